// Round 1
// 324.231 us; speedup vs baseline: 1.0373x; 1.0373x over previous
//
#include <hip/hip_runtime.h>

// ---------------------------------------------------------------------------
// LigerFusedNeighborhoodAttention on MI355X (gfx950)
// B=2, S=8192, H=1024, NH=16, HD=64, KERNEL=7, DILATION=1, SCALE=1/8
//
// Pipeline (4 launches):
//   1. prep: cast X fp32->bf16 + transpose 4 weights + bias concat (fused)
//   2. fused QKV GEMM (16384 x 3072 x 1024): 256x256 tile, BK=64, 512 thr,
//      8-phase schedule w/ counted vmcnt (T3+T4) + setprio (T5) + XOR-swizzled
//      LDS (T2) + XCD-bijective block swizzle (T1) -> QK row-major + Vt
//   3. MFMA banded attention (verified)
//   4. output GEMM (16384 x 1024 x 1024): 128x128 tile (m97 structure)
// ---------------------------------------------------------------------------

typedef __bf16 bf16x8 __attribute__((ext_vector_type(8)));
typedef float f32x4 __attribute__((ext_vector_type(4)));
typedef int int4v __attribute__((ext_vector_type(4)));
typedef __attribute__((address_space(1))) void as1_void;
typedef __attribute__((address_space(3))) void as3_void;

__device__ __forceinline__ float bf2f(unsigned short u) {
    union { unsigned int u; float f; } c;
    c.u = ((unsigned int)u) << 16;
    return c.f;
}
__device__ __forceinline__ unsigned short f2bf(float f) {
    union { float f; unsigned int u; } c;
    c.f = f;
    unsigned int u = c.u;
    u += 0x7fffu + ((u >> 16) & 1u);   // round-to-nearest-even
    return (unsigned short)(u >> 16);
}

// ------------- prep: cast X + transpose 4 weights + concat bias ------------
__global__ __launch_bounds__(256) void prep(
    const float* __restrict__ X, const float* __restrict__ w0,
    const float* __restrict__ w1, const float* __restrict__ w2,
    const float* __restrict__ w3, const float* __restrict__ bq,
    const float* __restrict__ bk, const float* __restrict__ bv,
    unsigned short* __restrict__ Xb, unsigned short* __restrict__ t0,
    unsigned short* __restrict__ t3, float* __restrict__ biasQ) {
    __shared__ unsigned short tile[32][33];
    const int bid = blockIdx.x;
    if (bid < 16384) {
        int i = bid * 256 + threadIdx.x;
        float4 v = ((const float4*)X)[i];
        ushort4 o;
        o.x = f2bf(v.x); o.y = f2bf(v.y); o.z = f2bf(v.z); o.w = f2bf(v.w);
        ((ushort4*)Xb)[i] = o;
    } else if (bid < 20480) {
        const int t = bid - 16384;
        const int z = t >> 10;
        const int rem = t & 1023;
        const float* W = (z == 0) ? w0 : (z == 1) ? w1 : (z == 2) ? w2 : w3;
        unsigned short* Wt = (z == 3) ? t3 : t0 + (size_t)z * 1048576;
        const int c0 = (rem & 31) * 32;
        const int r0 = (rem >> 5) * 32;
        const int tx = threadIdx.x & 31;
        const int ty = threadIdx.x >> 5;
#pragma unroll
        for (int i = 0; i < 32; i += 8)
            tile[ty + i][tx] = f2bf(W[(size_t)(r0 + ty + i) * 1024 + c0 + tx]);
        __syncthreads();
#pragma unroll
        for (int i = 0; i < 32; i += 8)
            Wt[(size_t)(c0 + ty + i) * 1024 + r0 + tx] = tile[tx][ty + i];
    } else {
        int i = (bid - 20480) * 256 + threadIdx.x;
        if (i < 3072)
            biasQ[i] = (i < 1024) ? bq[i] : ((i < 2048) ? bk[i - 1024] : bv[i - 2048]);
    }
}

// ------------------- QKV GEMM: 256x256 tile, 8-phase schedule --------------
// C(M,3072) = A(M,1024)*Bt(3072,1024)^T + bias.  512 threads = 8 waves (2Mx4N),
// per-wave 128x64 output = acc[8][4].  LDS 128 KB: 2 dbuf x [A 32KB | B 32KB].
// Per K-tile (BK=64): 4 phases, each {ds_read subtile | stage 1 half-tile |
// s_barrier | lgkmcnt(0) | setprio(1) 16 MFMA setprio(0) | s_barrier}.
// Staging: ph1->A0(t+1), ph2->A1(t+1), ph3->B0(t+2), ph4->B1(t+2)+vmcnt(4).
// vmcnt(4) = 2 half-tiles in flight => all of tile t+1 landed; never 0 in loop.
// Tail: staged k clamped to last tile (redundant L2-hit reads, never read back).
__global__ __launch_bounds__(512, 2) void gemm_qkv8(
    const unsigned short* __restrict__ A, const unsigned short* __restrict__ Bt,
    const float* __restrict__ bias, unsigned short* __restrict__ Cb,
    unsigned short* __restrict__ Vt) {
    constexpr int K = 1024;
    constexpr int NT = 16;                     // K / 64
    __shared__ unsigned short smem[65536];     // 128 KB
    const int tid  = threadIdx.x;
    const int lane = tid & 63;
    const int wave = tid >> 6;
    const int quad = lane >> 4;
    const int mr   = lane & 15;

    // XCD-bijective swizzle (768 blocks, 768 % 8 == 0)
    const int id  = blockIdx.x;
    const int swz = (id & 7) * 96 + (id >> 3);
    const int bm  = (swz / 12) * 256;
    const int bn  = (swz % 12) * 256;
    const int wm  = (wave >> 2) * 128;
    const int wn  = (wave & 3) * 64;

    // staging addresses: thread stages 16B granule pos (lane&7) of row r0(+64),
    // source granule XOR-swizzled by row (read side applies the same XOR).
    const int r0 = tid >> 3;
    const int g8 = ((lane & 7) ^ ((lane >> 3) & 7)) * 8;
    const unsigned short* srcA = A  + (size_t)(bm + r0) * K + g8;
    const unsigned short* srcB = Bt + (size_t)(bn + r0) * K + g8;

    auto stage = [&](const unsigned short* gb, int ldsByte, int kt) {
#pragma unroll
        for (int l = 0; l < 2; ++l)
            __builtin_amdgcn_global_load_lds(
                (const as1_void*)(gb + (size_t)l * 65536 + kt),   // +64 rows
                (as3_void*)((char*)smem + ldsByte + l * 8192 + tid * 16),
                16, 0, 0);
    };

    // prologue: tile0 {A0,A1,B0,B1} -> buf0; tile1 {B0,B1} -> buf1
    stage(srcA,          0,     0);
    stage(srcA + 131072, 16384, 0);
    stage(srcB,          32768, 0);
    stage(srcB + 131072, 49152, 0);
    stage(srcB,          65536 + 32768, 64);
    stage(srcB + 131072, 65536 + 49152, 64);
    asm volatile("s_waitcnt vmcnt(4)" ::: "memory");   // tile0 landed; B(1) in flight
    asm volatile("s_barrier" ::: "memory");

    const int aRow = (wm + mr) * 64;            // shorts, within A region
    const int bRow = 16384 + (wn + mr) * 64;    // shorts, within B region
    const int c8_0 = ((0 * 4 + quad) ^ (mr & 7)) * 8;
    const int c8_1 = ((1 * 4 + quad) ^ (mr & 7)) * 8;

    f32x4 acc[8][4] = {};
    bf16x8 af[4][2], b01[2][2], b23[2][2];

    for (int t = 0; t < NT; ++t) {
        const int bufS  = (t & 1) << 15;           // current buf (shorts)
        const int nbufB = ((t + 1) & 1) << 16;     // next buf (bytes)
        const int cbufB = (t & 1) << 16;           // current buf (bytes)
        const int ktA = (t + 1 < NT ? t + 1 : NT - 1) * 64;
        const int ktB = (t + 2 < NT ? t + 2 : NT - 1) * 64;

        // ---------------- phase 1: quadrant (M0 x N0); stage A0(t+1) -------
#pragma unroll
        for (int i = 0; i < 4; ++i) {
            af[i][0] = *(const bf16x8*)(smem + bufS + aRow + i * 1024 + c8_0);
            af[i][1] = *(const bf16x8*)(smem + bufS + aRow + i * 1024 + c8_1);
        }
#pragma unroll
        for (int j = 0; j < 2; ++j) {
            b01[j][0] = *(const bf16x8*)(smem + bufS + bRow + j * 1024 + c8_0);
            b01[j][1] = *(const bf16x8*)(smem + bufS + bRow + j * 1024 + c8_1);
        }
        stage(srcA, nbufB, ktA);
        asm volatile("s_barrier" ::: "memory");
        asm volatile("s_waitcnt lgkmcnt(0)" ::: "memory");
        __builtin_amdgcn_s_setprio(1);
#pragma unroll
        for (int i = 0; i < 4; ++i)
#pragma unroll
            for (int j = 0; j < 2; ++j) {
                acc[i][j] = __builtin_amdgcn_mfma_f32_16x16x32_bf16(af[i][0], b01[j][0], acc[i][j], 0, 0, 0);
                acc[i][j] = __builtin_amdgcn_mfma_f32_16x16x32_bf16(af[i][1], b01[j][1], acc[i][j], 0, 0, 0);
            }
        __builtin_amdgcn_s_setprio(0);
        asm volatile("s_barrier" ::: "memory");

        // ---------------- phase 2: quadrant (M0 x N1); stage A1(t+1) -------
#pragma unroll
        for (int j = 0; j < 2; ++j) {
            b23[j][0] = *(const bf16x8*)(smem + bufS + bRow + (j + 2) * 1024 + c8_0);
            b23[j][1] = *(const bf16x8*)(smem + bufS + bRow + (j + 2) * 1024 + c8_1);
        }
        stage(srcA + 131072, nbufB + 16384, ktA);
        asm volatile("s_barrier" ::: "memory");
        asm volatile("s_waitcnt lgkmcnt(0)" ::: "memory");
        __builtin_amdgcn_s_setprio(1);
#pragma unroll
        for (int i = 0; i < 4; ++i)
#pragma unroll
            for (int j = 0; j < 2; ++j) {
                acc[i][j + 2] = __builtin_amdgcn_mfma_f32_16x16x32_bf16(af[i][0], b23[j][0], acc[i][j + 2], 0, 0, 0);
                acc[i][j + 2] = __builtin_amdgcn_mfma_f32_16x16x32_bf16(af[i][1], b23[j][1], acc[i][j + 2], 0, 0, 0);
            }
        __builtin_amdgcn_s_setprio(0);
        asm volatile("s_barrier" ::: "memory");

        // ---------------- phase 3: quadrant (M1 x N1); stage B0(t+2) -------
#pragma unroll
        for (int i = 0; i < 4; ++i) {
            af[i][0] = *(const bf16x8*)(smem + bufS + aRow + (i + 4) * 1024 + c8_0);
            af[i][1] = *(const bf16x8*)(smem + bufS + aRow + (i + 4) * 1024 + c8_1);
        }
        stage(srcB, cbufB + 32768, ktB);
        asm volatile("s_barrier" ::: "memory");
        asm volatile("s_waitcnt lgkmcnt(0)" ::: "memory");
        __builtin_amdgcn_s_setprio(1);
#pragma unroll
        for (int i = 0; i < 4; ++i)
#pragma unroll
            for (int j = 0; j < 2; ++j) {
                acc[i + 4][j + 2] = __builtin_amdgcn_mfma_f32_16x16x32_bf16(af[i][0], b23[j][0], acc[i + 4][j + 2], 0, 0, 0);
                acc[i + 4][j + 2] = __builtin_amdgcn_mfma_f32_16x16x32_bf16(af[i][1], b23[j][1], acc[i + 4][j + 2], 0, 0, 0);
            }
        __builtin_amdgcn_s_setprio(0);
        asm volatile("s_barrier" ::: "memory");

        // ---------------- phase 4: quadrant (M1 x N0); stage B1(t+2) -------
        stage(srcB + 131072, cbufB + 49152, ktB);
        asm volatile("s_barrier" ::: "memory");
        asm volatile("s_waitcnt lgkmcnt(0)" ::: "memory");
        __builtin_amdgcn_s_setprio(1);
#pragma unroll
        for (int i = 0; i < 4; ++i)
#pragma unroll
            for (int j = 0; j < 2; ++j) {
                acc[i + 4][j] = __builtin_amdgcn_mfma_f32_16x16x32_bf16(af[i][0], b01[j][0], acc[i + 4][j], 0, 0, 0);
                acc[i + 4][j] = __builtin_amdgcn_mfma_f32_16x16x32_bf16(af[i][1], b01[j][1], acc[i + 4][j], 0, 0, 0);
            }
        __builtin_amdgcn_s_setprio(0);
        asm volatile("s_waitcnt vmcnt(4)" ::: "memory");   // tile t+1 fully landed
        asm volatile("s_barrier" ::: "memory");
    }

    // drain all staging before reusing LDS as epilogue scratch
    asm volatile("s_waitcnt vmcnt(0) lgkmcnt(0)" ::: "memory");
    asm volatile("s_barrier" ::: "memory");

    // ---------------- epilogue: per-wave 128x64, LDS bounce (stride 68) ----
    unsigned short* ep = smem + wave * 8192;   // 16 KB per wave
    if (bn < 2048) {
        // QK block: bf16 rows, stride 2048
#pragma unroll
        for (int h = 0; h < 2; ++h) {
#pragma unroll
            for (int j = 0; j < 4; ++j) {
                const float bvv = bias[bn + wn + j * 16 + mr];
#pragma unroll
                for (int i = 0; i < 4; ++i)
#pragma unroll
                    for (int r = 0; r < 4; ++r)
                        ep[(i * 16 + quad * 4 + r) * 68 + j * 16 + mr] =
                            f2bf(acc[h * 4 + i][j][r] + bvv);
            }
#pragma unroll
            for (int p = 0; p < 8; ++p) {
                const int row = p * 8 + (lane >> 3);
                const int gr = lane & 7;
                int4v v = *(const int4v*)(ep + row * 68 + gr * 8);
                *(int4v*)(Cb + (size_t)(bm + wm + h * 64 + row) * 2048 + bn + wn + gr * 8) = v;
            }
        }
    } else {
        // V block: transpose to Vt[b][h*64+d][s]
        const int bb = (bm + wm) >> 13;
        const int sb = (bm + wm) & 8191;
        const size_t vrow0 = (size_t)bb * 8388608 + (size_t)(bn - 2048 + wn) * 8192 + sb;
#pragma unroll
        for (int h = 0; h < 2; ++h) {
#pragma unroll
            for (int j = 0; j < 4; ++j) {
                const float bvv = bias[bn + wn + j * 16 + mr];
#pragma unroll
                for (int i = 0; i < 4; ++i)
#pragma unroll
                    for (int r = 0; r < 4; ++r)
                        ep[(j * 16 + mr) * 68 + h * 0 + i * 16 + quad * 4 + r] =
                            f2bf(acc[h * 4 + i][j][r] + bvv);
            }
#pragma unroll
            for (int p = 0; p < 8; ++p) {
                const int d = p * 8 + (lane >> 3);
                const int gr = lane & 7;
                int4v v = *(const int4v*)(ep + d * 68 + gr * 8);
                *(int4v*)(Vt + vrow0 + (size_t)d * 8192 + h * 64 + gr * 8) = v;
            }
        }
    }
}

// ------------------------------- MFMA GEMM (O-proj) ------------------------
template <int MODE, int MT>
__device__ __forceinline__ void gemm_body(
    const unsigned short* __restrict__ A, const unsigned short* __restrict__ Bt,
    const float* __restrict__ bias, float* __restrict__ Cf,
    unsigned short* __restrict__ Cb, unsigned short* __restrict__ Vt,
    int N, int K) {
    __shared__ unsigned short smem[MT * 2048 + 8192];
    const int tid = threadIdx.x;
    const int lane = tid & 63;
    const int wave = tid >> 6;
    const int bm = blockIdx.y * (MT * 32);
    const int bn = blockIdx.x * 128;
    const int wm = (wave >> 1) * (MT * 16);
    const int wn = (wave & 1) * 64;
    const int quad = lane >> 4;
    const int mr = lane & 15;

    const unsigned short* gA[MT];
    const unsigned short* gB[4];
    char* lA[MT];
    char* lB[4];
#pragma unroll
    for (int k = 0; k < MT; ++k) {
        const int q = (k * 4 + wave) * 64 + lane;
        const int row = q >> 3;
        const int c8 = (q & 7) ^ (row & 7);
        gA[k] = A + (size_t)(bm + row) * K + c8 * 8;
        lA[k] = (char*)smem + (size_t)(k * 4 + wave) * 1024;
    }
#pragma unroll
    for (int k = 0; k < 4; ++k) {
        const int q = (k * 4 + wave) * 64 + lane;
        const int row = q >> 3;
        const int c8 = (q & 7) ^ (row & 7);
        gB[k] = Bt + (size_t)(bn + row) * K + c8 * 8;
        lB[k] = (char*)smem + (size_t)MT * 4096 + (size_t)(k * 4 + wave) * 1024;
    }

    f32x4 acc[MT][4] = {};

    for (int kt = 0; kt < K; kt += 64) {
#pragma unroll
        for (int k = 0; k < MT; ++k) {
            __builtin_amdgcn_global_load_lds((as1_void*)gA[k], (as3_void*)lA[k], 16, 0, 0);
            gA[k] += 64;
        }
#pragma unroll
        for (int k = 0; k < 4; ++k) {
            __builtin_amdgcn_global_load_lds((as1_void*)gB[k], (as3_void*)lB[k], 16, 0, 0);
            gB[k] += 64;
        }
        __syncthreads();

#pragma unroll
        for (int kk = 0; kk < 2; ++kk) {
            const int c8 = (kk * 4 + quad) ^ (mr & 7);
            bf16x8 af[MT], bfr[4];
#pragma unroll
            for (int i = 0; i < MT; ++i)
                af[i] = *(const bf16x8*)(smem + (wm + i * 16 + mr) * 64 + c8 * 8);
#pragma unroll
            for (int j = 0; j < 4; ++j)
                bfr[j] = *(const bf16x8*)(smem + MT * 2048 + (wn + j * 16 + mr) * 64 + c8 * 8);
#pragma unroll
            for (int i = 0; i < MT; ++i)
#pragma unroll
                for (int j = 0; j < 4; ++j)
                    acc[i][j] = __builtin_amdgcn_mfma_f32_16x16x32_bf16(
                        af[i], bfr[j], acc[i][j], 0, 0, 0);
        }
        __syncthreads();
    }

    if (MODE == 0) {
        float* epf = (float*)smem + wave * 1280;
#pragma unroll
        for (int j = 0; j < 4; ++j) {
            const int gcol0 = bn + wn + j * 16;
            const float bv = bias[gcol0 + mr];
#pragma unroll
            for (int h2 = 0; h2 < MT / 4; ++h2) {
#pragma unroll
                for (int i2 = 0; i2 < 4; ++i2)
#pragma unroll
                    for (int r = 0; r < 4; ++r)
                        epf[(i2 * 16 + quad * 4 + r) * 20 + mr] = acc[h2 * 4 + i2][j][r] + bv;
#pragma unroll
                for (int p = 0; p < 4; ++p) {
                    const int dr = p * 16 + (lane >> 2);
                    const int ch = lane & 3;
                    f32x4 v = *(const f32x4*)(epf + dr * 20 + ch * 4);
                    *(f32x4*)(Cf + (size_t)(bm + wm + h2 * 64 + dr) * N + gcol0 + ch * 4) = v;
                }
            }
        }
    }
}

__global__ __launch_bounds__(256, 4) void gemm_out(
    const unsigned short* __restrict__ A, const unsigned short* __restrict__ Bt,
    const float* __restrict__ bias, float* __restrict__ Cf, int N, int K) {
    gemm_body<0, 4>(A, Bt, bias, Cf, nullptr, nullptr, N, K);
}

// --------------------------- MFMA banded attention -------------------------
__global__ __launch_bounds__(256) void attn_mfma(
    const unsigned short* __restrict__ QK, const unsigned short* __restrict__ Vt,
    unsigned short* __restrict__ out) {
    __shared__ unsigned short sP[4][64 * 104];
    const int tid = threadIdx.x;
    const int lane = tid & 63;
    const int wave = tid >> 6;
    const int quad = lane >> 4;
    const int cc = lane & 15;
    const int w = blockIdx.x * 4 + wave;
    const int b = w >> 11;
    const int h = (w >> 7) & 15;
    const int st = w & 127;
    const int s0 = st << 6;
    const int win0 = s0 - 8;
    const size_t tokBase = (size_t)b * 8192;
    unsigned short* P = sP[wave];

    {
        int4v z = {0, 0, 0, 0};
#pragma unroll
        for (int i = 0; i < 13; ++i)
            *(int4v*)(P + i * 512 + lane * 8) = z;
    }

    f32x4 accS[4][5] = {};
#pragma unroll
    for (int kc = 0; kc < 2; ++kc) {
        bf16x8 qf[4], kf[5];
#pragma unroll
        for (int mt = 0; mt < 4; ++mt)
            qf[mt] = *(const bf16x8*)(QK + (tokBase + s0 + mt * 16 + cc) * 2048
                                      + h * 64 + kc * 32 + quad * 8);
#pragma unroll
        for (int nt = 0; nt < 5; ++nt) {
            int row = win0 + nt * 16 + cc;
            row = row < 0 ? 0 : (row > 8191 ? 8191 : row);
            kf[nt] = *(const bf16x8*)(QK + (tokBase + row) * 2048
                                      + 1024 + h * 64 + kc * 32 + quad * 8);
        }
#pragma unroll
        for (int mt = 0; mt < 4; ++mt)
#pragma unroll
            for (int nt = 0; nt < 5; ++nt)
                accS[mt][nt] = __builtin_amdgcn_mfma_f32_16x16x32_bf16(
                    qf[mt], kf[nt], accS[mt][nt], 0, 0, 0);
    }

    const float NEG = -__builtin_inff();
#pragma unroll
    for (int mt = 0; mt < 4; ++mt) {
#pragma unroll
        for (int r = 0; r < 4; ++r) {
            const int mrow = mt * 16 + quad * 4 + r;
            float v[5];
#pragma unroll
            for (int nt = 0; nt < 5; ++nt) {
                const int k = nt * 16 + cc;
                const int rel = k - mrow;
                const int sidx = win0 + k;
                const bool ok = (rel >= 5) & (rel <= 11) & (sidx >= 0) & (sidx < 8192);
                v[nt] = ok ? accS[mt][nt][r] * 0.125f : NEG;
            }
            float mx = v[0];
#pragma unroll
            for (int nt = 1; nt < 5; ++nt) mx = fmaxf(mx, v[nt]);
#pragma unroll
            for (int off = 8; off >= 1; off >>= 1) mx = fmaxf(mx, __shfl_xor(mx, off));
            float p[5], sum = 0.f;
#pragma unroll
            for (int nt = 0; nt < 5; ++nt) {
                p[nt] = __builtin_amdgcn_exp2f((v[nt] - mx) * 1.44269504f);
                sum += p[nt];
            }
#pragma unroll
            for (int off = 8; off >= 1; off >>= 1) sum += __shfl_xor(sum, off);
            const float inv = __builtin_amdgcn_rcpf(sum);
#pragma unroll
            for (int nt = 0; nt < 5; ++nt)
                P[mrow * 104 + nt * 16 + cc] = f2bf(p[nt] * inv);
        }
    }

    f32x4 accO[4][4] = {};
#pragma unroll
    for (int kc = 0; kc < 3; ++kc) {
        bf16x8 pf[4], vf[4];
#pragma unroll
        for (int mt = 0; mt < 4; ++mt)
            pf[mt] = *(const bf16x8*)(P + (mt * 16 + cc) * 104 + kc * 32 + quad * 8);
        {
            int pos = win0 + kc * 32 + quad * 8;
            pos = pos < 0 ? 0 : (pos > 8184 ? 8184 : pos);
#pragma unroll
            for (int nt = 0; nt < 4; ++nt)
                vf[nt] = *(const bf16x8*)(Vt + ((size_t)(b * 16 + h) * 64 + nt * 16 + cc) * 8192 + pos);
        }
#pragma unroll
        for (int mt = 0; mt < 4; ++mt)
#pragma unroll
            for (int nt = 0; nt < 4; ++nt)
                accO[mt][nt] = __builtin_amdgcn_mfma_f32_16x16x32_bf16(
                    pf[mt], vf[nt], accO[mt][nt], 0, 0, 0);
    }

#pragma unroll
    for (int mt = 0; mt < 4; ++mt)
#pragma unroll
        for (int nt = 0; nt < 4; ++nt)
#pragma unroll
            for (int r = 0; r < 4; ++r)
                P[(mt * 16 + quad * 4 + r) * 72 + nt * 16 + cc] = f2bf(accO[mt][nt][r]);

#pragma unroll
    for (int pass = 0; pass < 8; ++pass) {
        const int row = pass * 8 + (lane >> 3);
        const int ch = lane & 7;
        int4v vv = *(const int4v*)(P + row * 72 + ch * 8);
        *(int4v*)(out + (tokBase + s0 + row) * 1024 + h * 64 + ch * 8) = vv;
    }
}

// ------------------------------- launch ------------------------------------
extern "C" void kernel_launch(void* const* d_in, const int* in_sizes, int n_in,
                              void* d_out, int out_size, void* d_ws, size_t ws_size,
                              hipStream_t stream) {
    (void)in_sizes; (void)n_in; (void)out_size; (void)ws_size;
    const float* X  = (const float*)d_in[0];
    const float* wq = (const float*)d_in[1];
    const float* bq = (const float*)d_in[2];
    const float* wk = (const float*)d_in[3];
    const float* bk = (const float*)d_in[4];
    const float* wv = (const float*)d_in[5];
    const float* bv = (const float*)d_in[6];
    const float* wo = (const float*)d_in[7];
    const float* bo = (const float*)d_in[8];
    float* out = (float*)d_out;

    char* ws = (char*)d_ws;
    unsigned short* Xb    = (unsigned short*)(ws);                 // 32 MB
    unsigned short* WtQKV = (unsigned short*)(ws + 33554432);      // 6 MB
    unsigned short* WtO   = (unsigned short*)(ws + 39845888);      // 2 MB
    unsigned short* QK    = (unsigned short*)(ws + 41943040);      // 64 MB
    unsigned short* Vt    = (unsigned short*)(ws + 109051904);     // 32 MB
    unsigned short* AttnO = (unsigned short*)(ws + 142606336);     // 32 MB
    float*          biasQ = (float*)(ws + 176160768);              // 12 KB

    prep<<<20492, 256, 0, stream>>>(X, wq, wk, wv, wo, bq, bk, bv,
                                    Xb, WtQKV, WtO, biasQ);

    // QKV: M=16384, N=3072, K=1024 -> QK + Vt   (256x256 tiles, 768 blocks)
    gemm_qkv8<<<768, 512, 0, stream>>>(Xb, WtQKV, biasQ, QK, Vt);

    // attention: 4096 waves = 1024 blocks
    attn_mfma<<<1024, 256, 0, stream>>>(QK, Vt, AttnO);

    // O-proj: M=16384, N=1024, K=1024, fp32 out  (128x128 tiles, 1024 blocks)
    gemm_out<<<dim3(8, 128), 256, 0, stream>>>(AttnO, WtO, bo, out, 1024, 1024);
}

// Round 2
// 313.863 us; speedup vs baseline: 1.0716x; 1.0330x over previous
//
#include <hip/hip_runtime.h>

// ---------------------------------------------------------------------------
// LigerFusedNeighborhoodAttention on MI355X (gfx950)
// B=2, S=8192, H=1024, NH=16, HD=64, KERNEL=7, DILATION=1, SCALE=1/8
//
// Pipeline (4 launches):
//   1. prep: cast X fp32->bf16 + transpose 4 weights + bias concat (fused)
//   2. fused QKV GEMM (16384 x 3072 x 1024): 256x256 tile, BK=64, 512 thr,
//      READ-AHEAD 4-phase schedule: loads issued before MFMA, compiler emits
//      counted lgkmcnt; 1 barrier/phase; vmcnt(4) once per K-tile (T3+T4);
//      setprio (T5); XOR-swizzled LDS (T2); XCD-bijective swizzle (T1)
//   3. MFMA banded attention (verified)
//   4. output GEMM (16384 x 1024 x 1024): 128x128 tile (m97 structure)
// ---------------------------------------------------------------------------

typedef __bf16 bf16x8 __attribute__((ext_vector_type(8)));
typedef float f32x4 __attribute__((ext_vector_type(4)));
typedef int int4v __attribute__((ext_vector_type(4)));
typedef __attribute__((address_space(1))) void as1_void;
typedef __attribute__((address_space(3))) void as3_void;

__device__ __forceinline__ float bf2f(unsigned short u) {
    union { unsigned int u; float f; } c;
    c.u = ((unsigned int)u) << 16;
    return c.f;
}
__device__ __forceinline__ unsigned short f2bf(float f) {
    union { float f; unsigned int u; } c;
    c.f = f;
    unsigned int u = c.u;
    u += 0x7fffu + ((u >> 16) & 1u);   // round-to-nearest-even
    return (unsigned short)(u >> 16);
}

// ------------- prep: cast X + transpose 4 weights + concat bias ------------
__global__ __launch_bounds__(256) void prep(
    const float* __restrict__ X, const float* __restrict__ w0,
    const float* __restrict__ w1, const float* __restrict__ w2,
    const float* __restrict__ w3, const float* __restrict__ bq,
    const float* __restrict__ bk, const float* __restrict__ bv,
    unsigned short* __restrict__ Xb, unsigned short* __restrict__ t0,
    unsigned short* __restrict__ t3, float* __restrict__ biasQ) {
    __shared__ unsigned short tile[32][33];
    const int bid = blockIdx.x;
    if (bid < 16384) {
        int i = bid * 256 + threadIdx.x;
        float4 v = ((const float4*)X)[i];
        ushort4 o;
        o.x = f2bf(v.x); o.y = f2bf(v.y); o.z = f2bf(v.z); o.w = f2bf(v.w);
        ((ushort4*)Xb)[i] = o;
    } else if (bid < 20480) {
        const int t = bid - 16384;
        const int z = t >> 10;
        const int rem = t & 1023;
        const float* W = (z == 0) ? w0 : (z == 1) ? w1 : (z == 2) ? w2 : w3;
        unsigned short* Wt = (z == 3) ? t3 : t0 + (size_t)z * 1048576;
        const int c0 = (rem & 31) * 32;
        const int r0 = (rem >> 5) * 32;
        const int tx = threadIdx.x & 31;
        const int ty = threadIdx.x >> 5;
#pragma unroll
        for (int i = 0; i < 32; i += 8)
            tile[ty + i][tx] = f2bf(W[(size_t)(r0 + ty + i) * 1024 + c0 + tx]);
        __syncthreads();
#pragma unroll
        for (int i = 0; i < 32; i += 8)
            Wt[(size_t)(c0 + ty + i) * 1024 + r0 + tx] = tile[tx][ty + i];
    } else {
        int i = (bid - 20480) * 256 + threadIdx.x;
        if (i < 3072)
            biasQ[i] = (i < 1024) ? bq[i] : ((i < 2048) ? bk[i - 1024] : bv[i - 2048]);
    }
}

// ------------- QKV GEMM: 256x256 tile, read-ahead 4-phase schedule ---------
// C(M,3072) = A(M,1024)*Bt(3072,1024)^T + bias.  512 threads = 8 waves (2Mx4N),
// per-wave 128x64 output = acc[8][4].  LDS 128 KB: 2 dbuf x [A 32KB | B 32KB].
// Per K-tile: ph1 {issue afL+bA+bB reads, stage A0(t+1), MFMA Q1(M0N0), bar}
//             ph2 {stage A1(t+1), MFMA Q2(M0N1) (bB had ph1 to land), bar}
//             ph3 {issue afH reads, stage B0(t+2), MFMA Q3(M1N1), bar}
//             ph4 {stage B1(t+2), MFMA Q4(M1N0) (all regs), vmcnt(4), bar}
// Compiler auto-emits counted lgkmcnt for the C++ ds_reads (no asm lgkm).
// Region safety: A(t+1)->other buffer; B(t+2) overwrites current-buffer B
// regions only after all B reads completed (pre-Q1/Q2) + barrier E2/E3.
// vmcnt(4) retires exactly tile t+1's 8 loads; B(t+2)'s 4 stay in flight.
__global__ __launch_bounds__(512, 2) void gemm_qkv8(
    const unsigned short* __restrict__ A, const unsigned short* __restrict__ Bt,
    const float* __restrict__ bias, unsigned short* __restrict__ Cb,
    unsigned short* __restrict__ Vt) {
    constexpr int K = 1024;
    constexpr int NT = 16;                     // K / 64
    __shared__ unsigned short smem[65536];     // 128 KB
    const int tid  = threadIdx.x;
    const int lane = tid & 63;
    const int wave = tid >> 6;
    const int quad = lane >> 4;
    const int mr   = lane & 15;

    // XCD-bijective swizzle (768 blocks, 768 % 8 == 0)
    const int id  = blockIdx.x;
    const int swz = (id & 7) * 96 + (id >> 3);
    const int bm  = (swz / 12) * 256;
    const int bn  = (swz % 12) * 256;
    const int wm  = (wave >> 2) * 128;
    const int wn  = (wave & 3) * 64;

    // staging addresses: thread stages 16B granule pos (lane&7) of row r0(+64),
    // source granule XOR-swizzled by row (read side applies the same XOR).
    const int r0 = tid >> 3;
    const int g8 = ((lane & 7) ^ ((lane >> 3) & 7)) * 8;
    const unsigned short* srcA = A  + (size_t)(bm + r0) * K + g8;
    const unsigned short* srcB = Bt + (size_t)(bn + r0) * K + g8;

    auto stage = [&](const unsigned short* gb, int ldsByte, int kt) {
#pragma unroll
        for (int l = 0; l < 2; ++l)
            __builtin_amdgcn_global_load_lds(
                (const as1_void*)(gb + (size_t)l * 65536 + kt),   // +64 rows
                (as3_void*)((char*)smem + ldsByte + l * 8192 + tid * 16),
                16, 0, 0);
    };

    // prologue: tile0 {A0,A1,B0,B1} -> buf0; tile1 {B0,B1} -> buf1
    stage(srcA,          0,     0);
    stage(srcA + 131072, 16384, 0);
    stage(srcB,          32768, 0);
    stage(srcB + 131072, 49152, 0);
    stage(srcB,          65536 + 32768, 64);
    stage(srcB + 131072, 65536 + 49152, 64);
    asm volatile("s_waitcnt vmcnt(4)" ::: "memory");   // tile0 landed; B(1) in flight
    asm volatile("s_barrier" ::: "memory");

    const int aRow = (wm + mr) * 64;            // shorts, within A region
    const int bRow = 16384 + (wn + mr) * 64;    // shorts, within B region
    const int c8_0 = ((0 * 4 + quad) ^ (mr & 7)) * 8;
    const int c8_1 = ((1 * 4 + quad) ^ (mr & 7)) * 8;

    f32x4 acc[8][4] = {};

    for (int t = 0; t < NT; ++t) {
        const int bufS  = (t & 1) << 15;           // current buf (shorts)
        const int nbufB = ((t + 1) & 1) << 16;     // next buf (bytes)
        const int cbufB = (t & 1) << 16;           // current buf (bytes)
        const int ktA = (t + 1 < NT ? t + 1 : NT - 1) * 64;
        const int ktB = (t + 2 < NT ? t + 2 : NT - 1) * 64;

        // ---- phase 1: issue afL+bA+bB reads; stage A0(t+1); MFMA Q1(M0N0) --
        bf16x8 afL[4][2], bA[2][2], bB[2][2];
#pragma unroll
        for (int i = 0; i < 4; ++i) {
            afL[i][0] = *(const bf16x8*)(smem + bufS + aRow + i * 1024 + c8_0);
            afL[i][1] = *(const bf16x8*)(smem + bufS + aRow + i * 1024 + c8_1);
        }
#pragma unroll
        for (int j = 0; j < 2; ++j) {
            bA[j][0] = *(const bf16x8*)(smem + bufS + bRow + j * 1024 + c8_0);
            bA[j][1] = *(const bf16x8*)(smem + bufS + bRow + j * 1024 + c8_1);
        }
#pragma unroll
        for (int j = 0; j < 2; ++j) {
            bB[j][0] = *(const bf16x8*)(smem + bufS + bRow + (j + 2) * 1024 + c8_0);
            bB[j][1] = *(const bf16x8*)(smem + bufS + bRow + (j + 2) * 1024 + c8_1);
        }
        stage(srcA, nbufB, ktA);
        __builtin_amdgcn_s_setprio(1);
#pragma unroll
        for (int i = 0; i < 4; ++i)
#pragma unroll
            for (int j = 0; j < 2; ++j) {
                acc[i][j] = __builtin_amdgcn_mfma_f32_16x16x32_bf16(afL[i][0], bA[j][0], acc[i][j], 0, 0, 0);
                acc[i][j] = __builtin_amdgcn_mfma_f32_16x16x32_bf16(afL[i][1], bA[j][1], acc[i][j], 0, 0, 0);
            }
        __builtin_amdgcn_s_setprio(0);
        asm volatile("s_barrier" ::: "memory");   // E1

        // ---- phase 2: stage A1(t+1); MFMA Q2(M0N1) ------------------------
        stage(srcA + 131072, nbufB + 16384, ktA);
        __builtin_amdgcn_s_setprio(1);
#pragma unroll
        for (int i = 0; i < 4; ++i)
#pragma unroll
            for (int j = 0; j < 2; ++j) {
                acc[i][j + 2] = __builtin_amdgcn_mfma_f32_16x16x32_bf16(afL[i][0], bB[j][0], acc[i][j + 2], 0, 0, 0);
                acc[i][j + 2] = __builtin_amdgcn_mfma_f32_16x16x32_bf16(afL[i][1], bB[j][1], acc[i][j + 2], 0, 0, 0);
            }
        __builtin_amdgcn_s_setprio(0);
        asm volatile("s_barrier" ::: "memory");   // E2

        // ---- phase 3: issue afH reads; stage B0(t+2); MFMA Q3(M1N1) -------
        bf16x8 afH[4][2];
#pragma unroll
        for (int i = 0; i < 4; ++i) {
            afH[i][0] = *(const bf16x8*)(smem + bufS + aRow + (i + 4) * 1024 + c8_0);
            afH[i][1] = *(const bf16x8*)(smem + bufS + aRow + (i + 4) * 1024 + c8_1);
        }
        stage(srcB, cbufB + 32768, ktB);
        __builtin_amdgcn_s_setprio(1);
#pragma unroll
        for (int i = 0; i < 4; ++i)
#pragma unroll
            for (int j = 0; j < 2; ++j) {
                acc[i + 4][j + 2] = __builtin_amdgcn_mfma_f32_16x16x32_bf16(afH[i][0], bB[j][0], acc[i + 4][j + 2], 0, 0, 0);
                acc[i + 4][j + 2] = __builtin_amdgcn_mfma_f32_16x16x32_bf16(afH[i][1], bB[j][1], acc[i + 4][j + 2], 0, 0, 0);
            }
        __builtin_amdgcn_s_setprio(0);
        asm volatile("s_barrier" ::: "memory");   // E3

        // ---- phase 4: stage B1(t+2); MFMA Q4(M1N0); vmcnt(4) --------------
        stage(srcB + 131072, cbufB + 49152, ktB);
        __builtin_amdgcn_s_setprio(1);
#pragma unroll
        for (int i = 0; i < 4; ++i)
#pragma unroll
            for (int j = 0; j < 2; ++j) {
                acc[i + 4][j] = __builtin_amdgcn_mfma_f32_16x16x32_bf16(afH[i][0], bA[j][0], acc[i + 4][j], 0, 0, 0);
                acc[i + 4][j] = __builtin_amdgcn_mfma_f32_16x16x32_bf16(afH[i][1], bA[j][1], acc[i + 4][j], 0, 0, 0);
            }
        __builtin_amdgcn_s_setprio(0);
        asm volatile("s_waitcnt vmcnt(4)" ::: "memory");   // tile t+1 fully landed
        asm volatile("s_barrier" ::: "memory");   // E4
    }

    // drain all staging before reusing LDS as epilogue scratch
    asm volatile("s_waitcnt vmcnt(0) lgkmcnt(0)" ::: "memory");
    asm volatile("s_barrier" ::: "memory");

    // ---------------- epilogue: per-wave 128x64, LDS bounce (stride 68) ----
    unsigned short* ep = smem + wave * 8192;   // 16 KB per wave
    if (bn < 2048) {
        // QK block: bf16 rows, stride 2048
#pragma unroll
        for (int h = 0; h < 2; ++h) {
#pragma unroll
            for (int j = 0; j < 4; ++j) {
                const float bvv = bias[bn + wn + j * 16 + mr];
#pragma unroll
                for (int i = 0; i < 4; ++i)
#pragma unroll
                    for (int r = 0; r < 4; ++r)
                        ep[(i * 16 + quad * 4 + r) * 68 + j * 16 + mr] =
                            f2bf(acc[h * 4 + i][j][r] + bvv);
            }
#pragma unroll
            for (int p = 0; p < 8; ++p) {
                const int row = p * 8 + (lane >> 3);
                const int gr = lane & 7;
                int4v v = *(const int4v*)(ep + row * 68 + gr * 8);
                *(int4v*)(Cb + (size_t)(bm + wm + h * 64 + row) * 2048 + bn + wn + gr * 8) = v;
            }
        }
    } else {
        // V block: transpose to Vt[b][h*64+d][s]
        const int bb = (bm + wm) >> 13;
        const int sb = (bm + wm) & 8191;
        const size_t vrow0 = (size_t)bb * 8388608 + (size_t)(bn - 2048 + wn) * 8192 + sb;
#pragma unroll
        for (int h = 0; h < 2; ++h) {
#pragma unroll
            for (int j = 0; j < 4; ++j) {
                const float bvv = bias[bn + wn + j * 16 + mr];
#pragma unroll
                for (int i = 0; i < 4; ++i)
#pragma unroll
                    for (int r = 0; r < 4; ++r)
                        ep[(j * 16 + mr) * 68 + i * 16 + quad * 4 + r] =
                            f2bf(acc[h * 4 + i][j][r] + bvv);
            }
#pragma unroll
            for (int p = 0; p < 8; ++p) {
                const int d = p * 8 + (lane >> 3);
                const int gr = lane & 7;
                int4v v = *(const int4v*)(ep + d * 68 + gr * 8);
                *(int4v*)(Vt + vrow0 + (size_t)d * 8192 + h * 64 + gr * 8) = v;
            }
        }
    }
}

// ------------------------------- MFMA GEMM (O-proj) ------------------------
template <int MODE, int MT>
__device__ __forceinline__ void gemm_body(
    const unsigned short* __restrict__ A, const unsigned short* __restrict__ Bt,
    const float* __restrict__ bias, float* __restrict__ Cf,
    unsigned short* __restrict__ Cb, unsigned short* __restrict__ Vt,
    int N, int K) {
    __shared__ unsigned short smem[MT * 2048 + 8192];
    const int tid = threadIdx.x;
    const int lane = tid & 63;
    const int wave = tid >> 6;
    const int bm = blockIdx.y * (MT * 32);
    const int bn = blockIdx.x * 128;
    const int wm = (wave >> 1) * (MT * 16);
    const int wn = (wave & 1) * 64;
    const int quad = lane >> 4;
    const int mr = lane & 15;

    const unsigned short* gA[MT];
    const unsigned short* gB[4];
    char* lA[MT];
    char* lB[4];
#pragma unroll
    for (int k = 0; k < MT; ++k) {
        const int q = (k * 4 + wave) * 64 + lane;
        const int row = q >> 3;
        const int c8 = (q & 7) ^ (row & 7);
        gA[k] = A + (size_t)(bm + row) * K + c8 * 8;
        lA[k] = (char*)smem + (size_t)(k * 4 + wave) * 1024;
    }
#pragma unroll
    for (int k = 0; k < 4; ++k) {
        const int q = (k * 4 + wave) * 64 + lane;
        const int row = q >> 3;
        const int c8 = (q & 7) ^ (row & 7);
        gB[k] = Bt + (size_t)(bn + row) * K + c8 * 8;
        lB[k] = (char*)smem + (size_t)MT * 4096 + (size_t)(k * 4 + wave) * 1024;
    }

    f32x4 acc[MT][4] = {};

    for (int kt = 0; kt < K; kt += 64) {
#pragma unroll
        for (int k = 0; k < MT; ++k) {
            __builtin_amdgcn_global_load_lds((as1_void*)gA[k], (as3_void*)lA[k], 16, 0, 0);
            gA[k] += 64;
        }
#pragma unroll
        for (int k = 0; k < 4; ++k) {
            __builtin_amdgcn_global_load_lds((as1_void*)gB[k], (as3_void*)lB[k], 16, 0, 0);
            gB[k] += 64;
        }
        __syncthreads();

#pragma unroll
        for (int kk = 0; kk < 2; ++kk) {
            const int c8 = (kk * 4 + quad) ^ (mr & 7);
            bf16x8 af[MT], bfr[4];
#pragma unroll
            for (int i = 0; i < MT; ++i)
                af[i] = *(const bf16x8*)(smem + (wm + i * 16 + mr) * 64 + c8 * 8);
#pragma unroll
            for (int j = 0; j < 4; ++j)
                bfr[j] = *(const bf16x8*)(smem + MT * 2048 + (wn + j * 16 + mr) * 64 + c8 * 8);
#pragma unroll
            for (int i = 0; i < MT; ++i)
#pragma unroll
                for (int j = 0; j < 4; ++j)
                    acc[i][j] = __builtin_amdgcn_mfma_f32_16x16x32_bf16(
                        af[i], bfr[j], acc[i][j], 0, 0, 0);
        }
        __syncthreads();
    }

    if (MODE == 0) {
        float* epf = (float*)smem + wave * 1280;
#pragma unroll
        for (int j = 0; j < 4; ++j) {
            const int gcol0 = bn + wn + j * 16;
            const float bv = bias[gcol0 + mr];
#pragma unroll
            for (int h2 = 0; h2 < MT / 4; ++h2) {
#pragma unroll
                for (int i2 = 0; i2 < 4; ++i2)
#pragma unroll
                    for (int r = 0; r < 4; ++r)
                        epf[(i2 * 16 + quad * 4 + r) * 20 + mr] = acc[h2 * 4 + i2][j][r] + bv;
#pragma unroll
                for (int p = 0; p < 4; ++p) {
                    const int dr = p * 16 + (lane >> 2);
                    const int ch = lane & 3;
                    f32x4 v = *(const f32x4*)(epf + dr * 20 + ch * 4);
                    *(f32x4*)(Cf + (size_t)(bm + wm + h2 * 64 + dr) * N + gcol0 + ch * 4) = v;
                }
            }
        }
    }
}

__global__ __launch_bounds__(256, 4) void gemm_out(
    const unsigned short* __restrict__ A, const unsigned short* __restrict__ Bt,
    const float* __restrict__ bias, float* __restrict__ Cf, int N, int K) {
    gemm_body<0, 4>(A, Bt, bias, Cf, nullptr, nullptr, N, K);
}

// --------------------------- MFMA banded attention -------------------------
__global__ __launch_bounds__(256) void attn_mfma(
    const unsigned short* __restrict__ QK, const unsigned short* __restrict__ Vt,
    unsigned short* __restrict__ out) {
    __shared__ unsigned short sP[4][64 * 104];
    const int tid = threadIdx.x;
    const int lane = tid & 63;
    const int wave = tid >> 6;
    const int quad = lane >> 4;
    const int cc = lane & 15;
    const int w = blockIdx.x * 4 + wave;
    const int b = w >> 11;
    const int h = (w >> 7) & 15;
    const int st = w & 127;
    const int s0 = st << 6;
    const int win0 = s0 - 8;
    const size_t tokBase = (size_t)b * 8192;
    unsigned short* P = sP[wave];

    {
        int4v z = {0, 0, 0, 0};
#pragma unroll
        for (int i = 0; i < 13; ++i)
            *(int4v*)(P + i * 512 + lane * 8) = z;
    }

    f32x4 accS[4][5] = {};
#pragma unroll
    for (int kc = 0; kc < 2; ++kc) {
        bf16x8 qf[4], kf[5];
#pragma unroll
        for (int mt = 0; mt < 4; ++mt)
            qf[mt] = *(const bf16x8*)(QK + (tokBase + s0 + mt * 16 + cc) * 2048
                                      + h * 64 + kc * 32 + quad * 8);
#pragma unroll
        for (int nt = 0; nt < 5; ++nt) {
            int row = win0 + nt * 16 + cc;
            row = row < 0 ? 0 : (row > 8191 ? 8191 : row);
            kf[nt] = *(const bf16x8*)(QK + (tokBase + row) * 2048
                                      + 1024 + h * 64 + kc * 32 + quad * 8);
        }
#pragma unroll
        for (int mt = 0; mt < 4; ++mt)
#pragma unroll
            for (int nt = 0; nt < 5; ++nt)
                accS[mt][nt] = __builtin_amdgcn_mfma_f32_16x16x32_bf16(
                    qf[mt], kf[nt], accS[mt][nt], 0, 0, 0);
    }

    const float NEG = -__builtin_inff();
#pragma unroll
    for (int mt = 0; mt < 4; ++mt) {
#pragma unroll
        for (int r = 0; r < 4; ++r) {
            const int mrow = mt * 16 + quad * 4 + r;
            float v[5];
#pragma unroll
            for (int nt = 0; nt < 5; ++nt) {
                const int k = nt * 16 + cc;
                const int rel = k - mrow;
                const int sidx = win0 + k;
                const bool ok = (rel >= 5) & (rel <= 11) & (sidx >= 0) & (sidx < 8192);
                v[nt] = ok ? accS[mt][nt][r] * 0.125f : NEG;
            }
            float mx = v[0];
#pragma unroll
            for (int nt = 1; nt < 5; ++nt) mx = fmaxf(mx, v[nt]);
#pragma unroll
            for (int off = 8; off >= 1; off >>= 1) mx = fmaxf(mx, __shfl_xor(mx, off));
            float p[5], sum = 0.f;
#pragma unroll
            for (int nt = 0; nt < 5; ++nt) {
                p[nt] = __builtin_amdgcn_exp2f((v[nt] - mx) * 1.44269504f);
                sum += p[nt];
            }
#pragma unroll
            for (int off = 8; off >= 1; off >>= 1) sum += __shfl_xor(sum, off);
            const float inv = __builtin_amdgcn_rcpf(sum);
#pragma unroll
            for (int nt = 0; nt < 5; ++nt)
                P[mrow * 104 + nt * 16 + cc] = f2bf(p[nt] * inv);
        }
    }

    f32x4 accO[4][4] = {};
#pragma unroll
    for (int kc = 0; kc < 3; ++kc) {
        bf16x8 pf[4], vf[4];
#pragma unroll
        for (int mt = 0; mt < 4; ++mt)
            pf[mt] = *(const bf16x8*)(P + (mt * 16 + cc) * 104 + kc * 32 + quad * 8);
        {
            int pos = win0 + kc * 32 + quad * 8;
            pos = pos < 0 ? 0 : (pos > 8184 ? 8184 : pos);
#pragma unroll
            for (int nt = 0; nt < 4; ++nt)
                vf[nt] = *(const bf16x8*)(Vt + ((size_t)(b * 16 + h) * 64 + nt * 16 + cc) * 8192 + pos);
        }
#pragma unroll
        for (int mt = 0; mt < 4; ++mt)
#pragma unroll
            for (int nt = 0; nt < 4; ++nt)
                accO[mt][nt] = __builtin_amdgcn_mfma_f32_16x16x32_bf16(
                    pf[mt], vf[nt], accO[mt][nt], 0, 0, 0);
    }

#pragma unroll
    for (int mt = 0; mt < 4; ++mt)
#pragma unroll
        for (int nt = 0; nt < 4; ++nt)
#pragma unroll
            for (int r = 0; r < 4; ++r)
                P[(mt * 16 + quad * 4 + r) * 72 + nt * 16 + cc] = f2bf(accO[mt][nt][r]);

#pragma unroll
    for (int pass = 0; pass < 8; ++pass) {
        const int row = pass * 8 + (lane >> 3);
        const int ch = lane & 7;
        int4v vv = *(const int4v*)(P + row * 72 + ch * 8);
        *(int4v*)(out + (tokBase + s0 + row) * 1024 + h * 64 + ch * 8) = vv;
    }
}

// ------------------------------- launch ------------------------------------
extern "C" void kernel_launch(void* const* d_in, const int* in_sizes, int n_in,
                              void* d_out, int out_size, void* d_ws, size_t ws_size,
                              hipStream_t stream) {
    (void)in_sizes; (void)n_in; (void)out_size; (void)ws_size;
    const float* X  = (const float*)d_in[0];
    const float* wq = (const float*)d_in[1];
    const float* bq = (const float*)d_in[2];
    const float* wk = (const float*)d_in[3];
    const float* bk = (const float*)d_in[4];
    const float* wv = (const float*)d_in[5];
    const float* bv = (const float*)d_in[6];
    const float* wo = (const float*)d_in[7];
    const float* bo = (const float*)d_in[8];
    float* out = (float*)d_out;

    char* ws = (char*)d_ws;
    unsigned short* Xb    = (unsigned short*)(ws);                 // 32 MB
    unsigned short* WtQKV = (unsigned short*)(ws + 33554432);      // 6 MB
    unsigned short* WtO   = (unsigned short*)(ws + 39845888);      // 2 MB
    unsigned short* QK    = (unsigned short*)(ws + 41943040);      // 64 MB
    unsigned short* Vt    = (unsigned short*)(ws + 109051904);     // 32 MB
    unsigned short* AttnO = (unsigned short*)(ws + 142606336);     // 32 MB
    float*          biasQ = (float*)(ws + 176160768);              // 12 KB

    prep<<<20492, 256, 0, stream>>>(X, wq, wk, wv, wo, bq, bk, bv,
                                    Xb, WtQKV, WtO, biasQ);

    // QKV: M=16384, N=3072, K=1024 -> QK + Vt   (256x256 tiles, 768 blocks)
    gemm_qkv8<<<768, 512, 0, stream>>>(Xb, WtQKV, biasQ, QK, Vt);

    // attention: 4096 waves = 1024 blocks
    attn_mfma<<<1024, 256, 0, stream>>>(QK, Vt, AttnO);

    // O-proj: M=16384, N=1024, K=1024, fp32 out  (128x128 tiles, 1024 blocks)
    gemm_out<<<dim3(8, 128), 256, 0, stream>>>(AttnO, WtO, bo, out, 1024, 1024);
}